// Round 1
// baseline (320.990 us; speedup 1.0000x reference)
//
#include <hip/hip_runtime.h>
#include <hip/hip_bf16.h>

#define NDIM 256
#define NROT 32640        // C(256,2)
#define NSEG 32
#define SEGLEN 1020       // 32640 / 32
#define MATF (NDIM * NDIM)  // floats per matrix

typedef __bf16 bf16x4_t __attribute__((ext_vector_type(4)));
typedef __bf16 bf16x8_t __attribute__((ext_vector_type(8)));
typedef float f32x4_t __attribute__((ext_vector_type(4)));

// ---------------------------------------------------------------------------
// K1: precompute cos/sin for all rotations
// ---------------------------------------------------------------------------
__global__ void k_sincos(const float* __restrict__ rots, float2* __restrict__ cs) {
    int k = blockIdx.x * 256 + threadIdx.x;
    if (k < NROT) {
        float th = rots[k];
        float s, c;
        sincosf(th, &s, &c);   // accurate versions (not __sincosf): errors compose over 32640 rotations
        cs[k] = make_float2(c, s);
    }
}

// ---------------------------------------------------------------------------
// K2: build NSEG segment products P_s = (product of rotations k in [s*SEGLEN, (s+1)*SEGLEN)) @ I
// Relies on idx being exactly lexicographic combinations(range(256), 2):
//   run i covers j = i+1..255, so row i stays in a register for the whole run
//   and the j-rows are mutually distinct within a run (safe to batch 8).
// Grid: NSEG*4 blocks of 64 threads; each block owns 64 columns (column-private,
// so no cross-thread hazards; LDS ops from one wave execute in order).
// ---------------------------------------------------------------------------
__global__ void k_build(const float2* __restrict__ cs, float* __restrict__ segout) {
    __shared__ float tile[NDIM * 64];   // 64 KiB: 256 rows x 64 cols
    const int t = threadIdx.x;          // 0..63
    const int seg = blockIdx.x >> 2;
    const int cg = blockIdx.x & 3;
    const int col = cg * 64 + t;

    for (int r = 0; r < NDIM; r++) tile[r * 64 + t] = (r == col) ? 1.0f : 0.0f;
    // single wave: LDS in-order, no barrier needed

    int k = seg * SEGLEN;
    const int kend = k + SEGLEN;
    // locate starting (i, j) for rotation index k
    int i = 0, cum = 0;
    while (cum + (NDIM - 1 - i) <= k) { cum += NDIM - 1 - i; i++; }
    int j = i + 1 + (k - cum);

    while (k < kend) {
        float ri = tile[i * 64 + t];
        int ntake = min(NDIM - j, kend - k);
        int jend = j + ntake;
        // batched by 8: 8 independent ds_reads pipeline their latency
        for (; j + 8 <= jend; j += 8, k += 8) {
            float rj[8];
            #pragma unroll
            for (int u = 0; u < 8; u++) rj[u] = tile[(j + u) * 64 + t];
            #pragma unroll
            for (int u = 0; u < 8; u++) {
                float2 cv = cs[k + u];
                float nri = fmaf(cv.x, ri, -(cv.y * rj[u]));
                rj[u]     = fmaf(cv.y, ri,  cv.x * rj[u]);
                ri = nri;
            }
            #pragma unroll
            for (int u = 0; u < 8; u++) tile[(j + u) * 64 + t] = rj[u];
        }
        for (; j < jend; j++, k++) {
            float2 cv = cs[k];
            float rj = tile[j * 64 + t];
            float nri = fmaf(cv.x, ri, -(cv.y * rj));
            tile[j * 64 + t] = fmaf(cv.y, ri, cv.x * rj);
            ri = nri;
        }
        tile[i * 64 + t] = ri;
        if (j == NDIM) { i++; j = i + 1; }
    }

    float* dst = segout + (size_t)seg * MATF;
    for (int r = 0; r < NDIM; r++) dst[r * NDIM + col] = tile[r * 64 + t];
}

// ---------------------------------------------------------------------------
// K3: pairwise tree combine: dst[p] = src[2p+1] @ src[2p]  (fp32, 256x256x256)
// Block computes RPB rows x 256 cols of one output; grid = npairs*(256/RPB) = 256.
// ---------------------------------------------------------------------------
template <int RPB>
__global__ void k_combine(const float* __restrict__ src, float* __restrict__ dst, int npairs) {
    const int blocksPerMat = NDIM / RPB;
    const int p = blockIdx.x / blocksPerMat;
    const int rb = blockIdx.x % blocksPerMat;
    const float* A = src + (size_t)(2 * p) * MATF;       // applied first (right factor)
    const float* B = src + (size_t)(2 * p + 1) * MATF;   // left factor
    float* C = dst + (size_t)p * MATF;
    const int r0 = rb * RPB;
    const int t = threadIdx.x;

    __shared__ float As[32 * NDIM];     // 32 k-rows x 256 cols = 32 KiB
    __shared__ float Bs[RPB][33];       // +1 pad

    float acc[RPB];
    #pragma unroll
    for (int r = 0; r < RPB; r++) acc[r] = 0.0f;

    for (int kc = 0; kc < NDIM; kc += 32) {
        __syncthreads();
        #pragma unroll
        for (int q = 0; q < 8; q++) {
            int fi = t + q * 256;       // 0..2047 float4's
            *(f32x4_t*)&As[fi * 4] = *(const f32x4_t*)&A[(size_t)kc * NDIM + fi * 4];
        }
        for (int idx = t; idx < RPB * 32; idx += 256) {
            int r = idx >> 5, kk = idx & 31;
            Bs[r][kk] = B[(size_t)(r0 + r) * NDIM + kc + kk];
        }
        __syncthreads();
        #pragma unroll
        for (int kk = 0; kk < 32; kk++) {
            float a = As[kk * NDIM + t];
            #pragma unroll
            for (int r = 0; r < RPB; r++) acc[r] = fmaf(Bs[r][kk], a, acc[r]);
        }
    }
    #pragma unroll
    for (int r = 0; r < RPB; r++) C[(size_t)(r0 + r) * NDIM + t] = acc[r];
}

// ---------------------------------------------------------------------------
// K4: Y[b][c] = sum_k X[b][k] * M[c][k]   (both K-contiguous, "B^T" GEMM)
// bf16 MFMA 16x16x32, BM=128 BN=128 BK=32, 256 threads = 4 waves (2x2 of 64x64).
// fp32->bf16 conversion during LDS staging; LDS stride 40 elems kills the
// power-of-2 b128 bank conflict. XCD swizzle puts both n-tiles of an m-block
// on the same XCD for L2 reuse of x.
// ---------------------------------------------------------------------------
#define LD 40
__global__ __launch_bounds__(256, 2) void k_gemm(const float* __restrict__ X,
                                                 const float* __restrict__ Mmat,
                                                 float* __restrict__ Y) {
    __shared__ __bf16 As[128 * LD];
    __shared__ __bf16 Bs[128 * LD];
    const int bx = blockIdx.x;
    const int xcd = bx & 7;
    const int q = bx >> 3;
    const int bn = (q & 1) * 128;
    const int bm = (xcd + (q >> 1) * 8) * 128;
    const int t = threadIdx.x;
    const int wid = t >> 6;
    const int lane = t & 63;
    const int wr = (wid >> 1) * 64;
    const int wc = (wid & 1) * 64;
    const int lrow = lane & 15;
    const int kg = lane >> 4;

    f32x4_t acc[4][4] = {};

    for (int kc = 0; kc < 256; kc += 32) {
        __syncthreads();
        #pragma unroll
        for (int qq = 0; qq < 4; qq++) {
            int fi = t + qq * 256;          // 0..1023
            int row = fi >> 3, sg = fi & 7; // 128 rows x 8 float4-segments
            f32x4_t v = *(const f32x4_t*)&X[(size_t)(bm + row) * 256 + kc + sg * 4];
            bf16x4_t h = {(__bf16)v.x, (__bf16)v.y, (__bf16)v.z, (__bf16)v.w};
            *(bf16x4_t*)&As[row * LD + sg * 4] = h;
        }
        #pragma unroll
        for (int qq = 0; qq < 4; qq++) {
            int fi = t + qq * 256;
            int row = fi >> 3, sg = fi & 7;
            f32x4_t v = *(const f32x4_t*)&Mmat[(size_t)(bn + row) * 256 + kc + sg * 4];
            bf16x4_t h = {(__bf16)v.x, (__bf16)v.y, (__bf16)v.z, (__bf16)v.w};
            *(bf16x4_t*)&Bs[row * LD + sg * 4] = h;
        }
        __syncthreads();

        bf16x8_t af[4], bfr[4];
        #pragma unroll
        for (int mt = 0; mt < 4; mt++)
            af[mt] = *(const bf16x8_t*)&As[(wr + mt * 16 + lrow) * LD + kg * 8];
        #pragma unroll
        for (int nt = 0; nt < 4; nt++)
            bfr[nt] = *(const bf16x8_t*)&Bs[(wc + nt * 16 + lrow) * LD + kg * 8];
        #pragma unroll
        for (int mt = 0; mt < 4; mt++)
            #pragma unroll
            for (int nt = 0; nt < 4; nt++)
                acc[mt][nt] = __builtin_amdgcn_mfma_f32_16x16x32_bf16(af[mt], bfr[nt], acc[mt][nt], 0, 0, 0);
    }

    // C/D layout: col = lane&15, row = (lane>>4)*4 + reg (m89-verified)
    const int ocol = bn + wc + lrow;
    const int orow = bm + wr + kg * 4;
    #pragma unroll
    for (int mt = 0; mt < 4; mt++)
        #pragma unroll
        for (int nt = 0; nt < 4; nt++)
            #pragma unroll
            for (int r = 0; r < 4; r++)
                Y[(size_t)(orow + mt * 16 + r) * 256 + ocol + nt * 16] = acc[mt][nt][r];
}

// ---------------------------------------------------------------------------
// workspace layout (floats):
//   [0, 65536)                       cs (float2 x 32640, padded)
//   [65536, 65536+32*65536)          B0: 32 segment matrices
//   [B0end, B0end+16*65536)          B1: tree buffer
// total = 3,211,264 floats = 12.25 MiB
// ---------------------------------------------------------------------------
extern "C" void kernel_launch(void* const* d_in, const int* in_sizes, int n_in,
                              void* d_out, int out_size, void* d_ws, size_t ws_size,
                              hipStream_t stream) {
    const float* x = (const float*)d_in[0];
    const float* rots = (const float*)d_in[1];
    // d_in[2]/d_in[3] (idx_i/idx_j) are lexicographic combinations(256,2) — derived analytically
    float* out = (float*)d_out;
    float* ws = (float*)d_ws;

    float2* cs = (float2*)ws;
    float* B0 = ws + 65536;
    float* B1 = B0 + (size_t)NSEG * MATF;

    k_sincos<<<128, 256, 0, stream>>>(rots, cs);
    k_build<<<NSEG * 4, 64, 0, stream>>>(cs, B0);
    // tree combine: 32 -> 16 -> 8 -> 4 -> 2 -> 1
    k_combine<16><<<256, 256, 0, stream>>>(B0, B1, 16);
    k_combine<8><<<256, 256, 0, stream>>>(B1, B0, 8);
    k_combine<4><<<256, 256, 0, stream>>>(B0, B1, 4);
    k_combine<2><<<256, 256, 0, stream>>>(B1, B0, 2);
    k_combine<1><<<256, 256, 0, stream>>>(B0, B1, 1);
    // final mat in B1[0]; y = x @ mat^T
    k_gemm<<<1024, 256, 0, stream>>>(x, B1, out);
}

// Round 3
// 263.046 us; speedup vs baseline: 1.2203x; 1.2203x over previous
//
#include <hip/hip_runtime.h>
#include <hip/hip_bf16.h>

#define NDIM 256
#define NROT 32640          // C(256,2)
#define NSEG 64
#define SEGLEN 510          // 64 * 510 == 32640 exactly
#define MATE (NDIM * NDIM)  // elements per matrix

typedef __bf16 bf16x4_t __attribute__((ext_vector_type(4)));
typedef __bf16 bf16x8_t __attribute__((ext_vector_type(8)));
typedef float f32x4_t __attribute__((ext_vector_type(4)));

// ---------------------------------------------------------------------------
// K1: precompute cos/sin for all rotations
// ---------------------------------------------------------------------------
__global__ void k_sincos(const float* __restrict__ rots, float2* __restrict__ cs) {
    int k = blockIdx.x * 256 + threadIdx.x;
    if (k < NROT) {
        float th = rots[k];
        float s, c;
        sincosf(th, &s, &c);
        cs[k] = make_float2(c, s);
    }
}

// ---------------------------------------------------------------------------
// K2: build 64 segment products P_s (510 rotations each) applied to I, fp32.
// Lexicographic combinations(256,2): within a run (fixed i), row i stays in a
// register; each j-row touched once. 2-deep software pipeline: group g+1's
// cs (global) and rj (LDS) loads issue before group g's FMA chain.
// Storage convention for the MFMA tree:
//   even seg -> TRANSPOSED (RHS-ready [c][k]); odd seg -> plain ([r][k]).
// ---------------------------------------------------------------------------
__global__ void k_build(const float2* __restrict__ cs, float* __restrict__ leaves) {
    __shared__ float tile[NDIM * 64];   // 64 KiB: 256 rows x 64 cols
    const int t = threadIdx.x;          // 0..63
    const int seg = blockIdx.x >> 2;
    const int cg = blockIdx.x & 3;
    const int col = cg * 64 + t;

    for (int r = 0; r < NDIM; r++) tile[r * 64 + t] = (r == col) ? 1.0f : 0.0f;
    // single wave: LDS ops execute in order, no barrier needed

    int k = seg * SEGLEN;
    const int kend = k + SEGLEN;
    int i = 0, cum = 0;
    while (cum + (NDIM - 1 - i) <= k) { cum += NDIM - 1 - i; i++; }
    int j = i + 1 + (k - cum);

    while (k < kend) {
        float ri = tile[i * 64 + t];
        int jend = j + min(NDIM - j, kend - k);

        if (j + 8 <= jend) {
            float2 cv[8]; float rj[8];
            #pragma unroll
            for (int u = 0; u < 8; u++) cv[u] = cs[k + u];
            #pragma unroll
            for (int u = 0; u < 8; u++) rj[u] = tile[(j + u) * 64 + t];
            while (true) {
                const bool more = (j + 16 <= jend);
                float2 cvn[8]; float rjn[8];
                if (more) {
                    #pragma unroll
                    for (int u = 0; u < 8; u++) cvn[u] = cs[k + 8 + u];
                    #pragma unroll
                    for (int u = 0; u < 8; u++) rjn[u] = tile[(j + 8 + u) * 64 + t];
                }
                #pragma unroll
                for (int u = 0; u < 8; u++) {
                    float nri = fmaf(cv[u].x, ri, -(cv[u].y * rj[u]));
                    rj[u]     = fmaf(cv[u].y, ri,  cv[u].x * rj[u]);
                    ri = nri;
                }
                #pragma unroll
                for (int u = 0; u < 8; u++) tile[(j + u) * 64 + t] = rj[u];
                j += 8; k += 8;
                if (!more) break;
                #pragma unroll
                for (int u = 0; u < 8; u++) { cv[u] = cvn[u]; rj[u] = rjn[u]; }
            }
        }
        for (; j < jend; j++, k++) {
            float2 cv = cs[k];
            float rj = tile[j * 64 + t];
            float nri = fmaf(cv.x, ri, -(cv.y * rj));
            tile[j * 64 + t] = fmaf(cv.y, ri, cv.x * rj);
            ri = nri;
        }
        tile[i * 64 + t] = ri;
        if (j == NDIM) { i++; j = i + 1; }
    }

    float* dst = leaves + (size_t)seg * MATE;
    if (seg & 1) {
        // plain row-major: coalesced stores, one row at a time
        for (int r = 0; r < NDIM; r++)
            dst[r * NDIM + col] = tile[r * 64 + t];
    } else {
        // transposed: thread owns one output row (its column), 16B stores
        for (int r0 = 0; r0 < NDIM; r0 += 4) {
            f32x4_t v = {tile[(r0 + 0) * 64 + t], tile[(r0 + 1) * 64 + t],
                         tile[(r0 + 2) * 64 + t], tile[(r0 + 3) * 64 + t]};
            *(f32x4_t*)&dst[(size_t)col * NDIM + r0] = v;
        }
    }
}

// ---------------------------------------------------------------------------
// K3: tree combine, SPLIT-PRECISION bf16 MFMA on fp32 storage.
// node[p] = child[2p+1] @ child[2p];  C ~= Bhi@Ahi + Bhi@Alo + Blo@Ahi
// (rel err ~2^-17 per level -> tree stays fp32-accurate).
// child[2p] transposed ([c][k]), child[2p+1] plain ([r][k]); output fp32,
// transposed if (!final && p even) else plain.
// Grid: npairs*4 blocks; each block one 128x128 quadrant; 4 waves 2x2.
// ---------------------------------------------------------------------------
#define LDB 40
__global__ __launch_bounds__(256) void k_combine(const float* __restrict__ src,
                                                 float* __restrict__ dst,
                                                 int finalLevel) {
    const int p = blockIdx.x >> 2;
    const int quad = blockIdx.x & 3;
    const int rb = (quad >> 1) * 128;
    const int cb = (quad & 1) * 128;
    const float* A = src + (size_t)(2 * p) * MATE;       // transposed child (RHS)
    const float* B = src + (size_t)(2 * p + 1) * MATE;   // plain child (LHS)
    float* C = dst + (size_t)p * MATE;
    const bool storeT = (!finalLevel) && ((p & 1) == 0);
    const int t = threadIdx.x;
    const int wid = t >> 6, lane = t & 63;
    const int wro = (wid >> 1) * 64, wco = (wid & 1) * 64;
    const int lrow = lane & 15, kg = lane >> 4;

    __shared__ __bf16 Bhi[128 * LDB];
    __shared__ __bf16 Blo[128 * LDB];
    __shared__ __bf16 Ahi[128 * LDB];
    __shared__ __bf16 Alo[128 * LDB];

    f32x4_t acc[4][4] = {};

    for (int kc = 0; kc < NDIM; kc += 32) {
        __syncthreads();
        #pragma unroll
        for (int qq = 0; qq < 4; qq++) {
            int fi = t + qq * 256;          // 0..1023
            int row = fi >> 3, sg = fi & 7; // 128 rows x 8 float4-segments
            f32x4_t vb = *(const f32x4_t*)&B[(size_t)(rb + row) * NDIM + kc + sg * 4];
            f32x4_t va = *(const f32x4_t*)&A[(size_t)(cb + row) * NDIM + kc + sg * 4];
            bf16x4_t bh = {(__bf16)vb.x, (__bf16)vb.y, (__bf16)vb.z, (__bf16)vb.w};
            bf16x4_t ah = {(__bf16)va.x, (__bf16)va.y, (__bf16)va.z, (__bf16)va.w};
            bf16x4_t bl = {(__bf16)(vb.x - (float)bh[0]), (__bf16)(vb.y - (float)bh[1]),
                           (__bf16)(vb.z - (float)bh[2]), (__bf16)(vb.w - (float)bh[3])};
            bf16x4_t al = {(__bf16)(va.x - (float)ah[0]), (__bf16)(va.y - (float)ah[1]),
                           (__bf16)(va.z - (float)ah[2]), (__bf16)(va.w - (float)ah[3])};
            *(bf16x4_t*)&Bhi[row * LDB + sg * 4] = bh;
            *(bf16x4_t*)&Blo[row * LDB + sg * 4] = bl;
            *(bf16x4_t*)&Ahi[row * LDB + sg * 4] = ah;
            *(bf16x4_t*)&Alo[row * LDB + sg * 4] = al;
        }
        __syncthreads();

        bf16x8_t afh[4], afl[4], bfh[4], bfl[4];
        #pragma unroll
        for (int mt = 0; mt < 4; mt++) {
            afh[mt] = *(const bf16x8_t*)&Bhi[(wro + mt * 16 + lrow) * LDB + kg * 8];
            afl[mt] = *(const bf16x8_t*)&Blo[(wro + mt * 16 + lrow) * LDB + kg * 8];
        }
        #pragma unroll
        for (int nt = 0; nt < 4; nt++) {
            bfh[nt] = *(const bf16x8_t*)&Ahi[(wco + nt * 16 + lrow) * LDB + kg * 8];
            bfl[nt] = *(const bf16x8_t*)&Alo[(wco + nt * 16 + lrow) * LDB + kg * 8];
        }
        #pragma unroll
        for (int mt = 0; mt < 4; mt++)
            #pragma unroll
            for (int nt = 0; nt < 4; nt++) {
                acc[mt][nt] = __builtin_amdgcn_mfma_f32_16x16x32_bf16(afh[mt], bfh[nt], acc[mt][nt], 0, 0, 0);
                acc[mt][nt] = __builtin_amdgcn_mfma_f32_16x16x32_bf16(afh[mt], bfl[nt], acc[mt][nt], 0, 0, 0);
                acc[mt][nt] = __builtin_amdgcn_mfma_f32_16x16x32_bf16(afl[mt], bfh[nt], acc[mt][nt], 0, 0, 0);
            }
    }

    // C/D layout: col = lane&15, row = (lane>>4)*4 + reg
    if (storeT) {
        #pragma unroll
        for (int mt = 0; mt < 4; mt++)
            #pragma unroll
            for (int nt = 0; nt < 4; nt++) {
                int gr = rb + wro + mt * 16 + kg * 4;
                int gc = cb + wco + nt * 16 + lrow;
                *(f32x4_t*)&C[(size_t)gc * NDIM + gr] = acc[mt][nt];
            }
    } else {
        #pragma unroll
        for (int mt = 0; mt < 4; mt++)
            #pragma unroll
            for (int nt = 0; nt < 4; nt++)
                #pragma unroll
                for (int r = 0; r < 4; r++)
                    C[(size_t)(rb + wro + mt * 16 + kg * 4 + r) * NDIM
                      + cb + wco + nt * 16 + lrow] = acc[mt][nt][r];
    }
}

// ---------------------------------------------------------------------------
// K4: Y[b][c] = sum_k X[b][k] * M[c][k]; M fp32 row-major (root), converted
// to bf16 during staging. BM=BN=128, BK=32, 4 waves 2x2.
// ---------------------------------------------------------------------------
#define LD 40
__global__ __launch_bounds__(256, 2) void k_gemm(const float* __restrict__ X,
                                                 const float* __restrict__ Mmat,
                                                 float* __restrict__ Y) {
    __shared__ __bf16 As[128 * LD];
    __shared__ __bf16 Bs[128 * LD];
    const int bx = blockIdx.x;
    const int xcd = bx & 7;
    const int q = bx >> 3;
    const int bn = (q & 1) * 128;
    const int bm = (xcd + (q >> 1) * 8) * 128;
    const int t = threadIdx.x;
    const int wid = t >> 6;
    const int lane = t & 63;
    const int wr = (wid >> 1) * 64;
    const int wc = (wid & 1) * 64;
    const int lrow = lane & 15;
    const int kg = lane >> 4;

    f32x4_t acc[4][4] = {};

    for (int kc = 0; kc < 256; kc += 32) {
        __syncthreads();
        #pragma unroll
        for (int qq = 0; qq < 4; qq++) {
            int fi = t + qq * 256;          // 0..1023
            int row = fi >> 3, sg = fi & 7;
            f32x4_t v = *(const f32x4_t*)&X[(size_t)(bm + row) * 256 + kc + sg * 4];
            bf16x4_t h = {(__bf16)v.x, (__bf16)v.y, (__bf16)v.z, (__bf16)v.w};
            *(bf16x4_t*)&As[row * LD + sg * 4] = h;
        }
        #pragma unroll
        for (int qq = 0; qq < 4; qq++) {
            int fi = t + qq * 256;
            int row = fi >> 3, sg = fi & 7;
            f32x4_t v = *(const f32x4_t*)&Mmat[(size_t)(bn + row) * 256 + kc + sg * 4];
            bf16x4_t h = {(__bf16)v.x, (__bf16)v.y, (__bf16)v.z, (__bf16)v.w};
            *(bf16x4_t*)&Bs[row * LD + sg * 4] = h;
        }
        __syncthreads();

        bf16x8_t af[4], bfr[4];
        #pragma unroll
        for (int mt = 0; mt < 4; mt++)
            af[mt] = *(const bf16x8_t*)&As[(wr + mt * 16 + lrow) * LD + kg * 8];
        #pragma unroll
        for (int nt = 0; nt < 4; nt++)
            bfr[nt] = *(const bf16x8_t*)&Bs[(wc + nt * 16 + lrow) * LD + kg * 8];
        #pragma unroll
        for (int mt = 0; mt < 4; mt++)
            #pragma unroll
            for (int nt = 0; nt < 4; nt++)
                acc[mt][nt] = __builtin_amdgcn_mfma_f32_16x16x32_bf16(af[mt], bfr[nt], acc[mt][nt], 0, 0, 0);
    }

    const int ocol = bn + wc + lrow;
    const int orow = bm + wr + kg * 4;
    #pragma unroll
    for (int mt = 0; mt < 4; mt++)
        #pragma unroll
        for (int nt = 0; nt < 4; nt++)
            #pragma unroll
            for (int r = 0; r < 4; r++)
                Y[(size_t)(orow + mt * 16 + r) * 256 + ocol + nt * 16] = acc[mt][nt][r];
}

// ---------------------------------------------------------------------------
// workspace (bytes):
//   [0, 256K)      cs (float2 x 32640)
//   B0: 64 fp32 mats (16 MB) ; B1: 32 fp32 mats (8 MB)  -> total 24.25 MB
// tree: B0(64 leaves) ->B1(32) ->B0(16) ->B1(8) ->B0(4) ->B1(2) ->B0(1=root)
// ---------------------------------------------------------------------------
extern "C" void kernel_launch(void* const* d_in, const int* in_sizes, int n_in,
                              void* d_out, int out_size, void* d_ws, size_t ws_size,
                              hipStream_t stream) {
    const float* x = (const float*)d_in[0];
    const float* rots = (const float*)d_in[1];
    float* out = (float*)d_out;

    char* wsb = (char*)d_ws;
    float2* cs = (float2*)wsb;
    float* B0 = (float*)(wsb + 262144);
    float* B1 = B0 + (size_t)NSEG * MATE;

    k_sincos<<<128, 256, 0, stream>>>(rots, cs);
    k_build<<<NSEG * 4, 64, 0, stream>>>(cs, B0);
    k_combine<<<32 * 4, 256, 0, stream>>>(B0, B1, 0);
    k_combine<<<16 * 4, 256, 0, stream>>>(B1, B0, 0);
    k_combine<<<8 * 4, 256, 0, stream>>>(B0, B1, 0);
    k_combine<<<4 * 4, 256, 0, stream>>>(B1, B0, 0);
    k_combine<<<2 * 4, 256, 0, stream>>>(B0, B1, 0);
    k_combine<<<1 * 4, 256, 0, stream>>>(B1, B0, 1);
    k_gemm<<<1024, 256, 0, stream>>>(x, B0, out);
}